// Round 10
// baseline (4964.565 us; speedup 1.0000x reference)
//
#include <hip/hip_runtime.h>
#include <cstdint>
#include <cstddef>

typedef float f32x4 __attribute__((ext_vector_type(4)));
typedef float f32x2 __attribute__((ext_vector_type(2)));
typedef unsigned int u32x4 __attribute__((ext_vector_type(4)));
typedef unsigned int u32x2 __attribute__((ext_vector_type(2)));
typedef short s16x8 __attribute__((ext_vector_type(8)));

#define H     1024
#define BATCH 16
#define SEQ   2000
#define NOUT  8
#define G     32       // persistent workgroups, 32 rows x ALL batches each
#define ROWS  32       // rows per WG
#define TPB   256

// d_out offsets (floats): n_all, h_all, r_all, u_all, z_all
#define H_OFF 32768000
#define R_OFF 65536000
#define U_OFF 98304000
#define Z_OFF 131072000

// ws layout (bytes)
#define SBUF_OFF  8192       // double-buffered packed s: 2*16384 u32, layout [j>>3][b][j&7]
#define IREP_OFF  139264     // I repacked [t][b] (+pad)
#define ZPART_OFF 267392     // zpart [t][g][b]: 2000*32*16 floats

#define TAG(tau) ((unsigned int)(((tau) >> 1) & 1))

__global__ void init_kernel(const float* __restrict__ I, float* __restrict__ Irep,
                            unsigned int* __restrict__ sbuf) {
  int tid = blockIdx.x * blockDim.x + threadIdx.x;
  if (tid < SEQ * BATCH) {
    int t = tid >> 4, b = tid & 15;
    Irep[tid] = I[b * SEQ + t];            // I is [B, SEQ, 1]
  }
  if (tid < 2 * BATCH * H) {               // pre-tag both buffers stale (LSB=1; fresh tags start at 0)
    unsigned int* ap = sbuf + tid; unsigned int v = 1u;
    asm volatile("global_store_dword %0, %1, off sc0 sc1" :: "v"(ap), "v"(v) : "memory");
  }
}

// split f into truncated-bf16 hi + truncated-bf16 lo, packed (hi<<16)|lo
__device__ __forceinline__ unsigned int pack_split(float f) {
  unsigned int uh = __float_as_uint(f) & 0xffff0000u;
  float fl = f - __uint_as_float(uh);
  return uh | (__float_as_uint(fl) >> 16);
}

__global__ __launch_bounds__(TPB, 1) void rnn_persist(
    const float* __restrict__ h0, const float* __restrict__ r0, const float* __restrict__ u0,
    const float* __restrict__ Wih, const float* __restrict__ offih,
    const float* __restrict__ Whh, const float* __restrict__ Whz,
    const float* __restrict__ prel, const float* __restrict__ Whhm, const float* __restrict__ Whzm,
    const float* __restrict__ Irep, unsigned int* __restrict__ sbuf,
    float* __restrict__ zpart, float* __restrict__ dout)
{
  __shared__ float redC[2][4][2][16][17];  // [parity][kwave][rowtile][row16][batch(+pad)]
  __shared__ float zsc[2][4][16];          // [parity][wave][batch] z partials (8 rows each)

  const int g = blockIdx.x, tid = threadIdx.x;
  const int lane = tid & 63, w = tid >> 6;
  const int arow  = lane & 15;             // MFMA A row / B col (batch)
  const int klane = lane >> 4;             // 0..3 within-wave k subgroup

  // ---- one-time: this WG's 32 masked W rows -> split-bf16 VGPR fragments ----
  // wave w covers K quarter [w*256,(w+1)*256); A row (lane) = g*32 + rt*16 + arow
  s16x8 ahi[2][8], alo[2][8];
  #pragma unroll
  for (int rt = 0; rt < 2; ++rt) {
    const float* wr = Whh  + (size_t)(g * ROWS + rt * 16 + arow) * H + w * 256 + klane * 8;
    const float* mr = Whhm + (size_t)(g * ROWS + rt * 16 + arow) * H + w * 256 + klane * 8;
    #pragma unroll
    for (int c = 0; c < 8; ++c) {
      f32x4 w0 = *(const f32x4*)(wr + c * 32),     m0 = *(const f32x4*)(mr + c * 32);
      f32x4 w1 = *(const f32x4*)(wr + c * 32 + 4), m1 = *(const f32x4*)(mr + c * 32 + 4);
      float wf[8] = { w0.x*m0.x, w0.y*m0.y, w0.z*m0.z, w0.w*m0.w,
                      w1.x*m1.x, w1.y*m1.y, w1.z*m1.z, w1.w*m1.w };
      #pragma unroll
      for (int i = 0; i < 8; ++i) {
        unsigned int uh = __float_as_uint(wf[i]) & 0xffff0000u;
        float fl = wf[i] - __uint_as_float(uh);
        ahi[rt][c][i] = (short)(uh >> 16);
        alo[rt][c][i] = (short)(__float_as_uint(fl) >> 16);
      }
    }
  }

  // ---- per-lane persistent state: 2 consecutive rows, one batch ----
  const int r0w = g * ROWS + w * 8 + 2 * klane;  // first owned row
  const int bo  = arow;                          // owned batch
  f32x2 hv = *(const f32x2*)(h0 + (size_t)bo * H + r0w);
  f32x2 rv = *(const f32x2*)(r0 + (size_t)bo * H + r0w);
  f32x2 uv = *(const f32x2*)(u0 + (size_t)bo * H + r0w);
  f32x2 pv = *(const f32x2*)(prel + r0w);
  f32x2 wihv = *(const f32x2*)(Wih + r0w);
  f32x2 oihv = *(const f32x2*)(offih + r0w);
  const int o = r0w >> 7;                        // whole WG maps to one output block
  f32x2 wzv  = *(const f32x2*)(Whz  + (size_t)o * H + r0w);
  f32x2 wzm  = *(const f32x2*)(Whzm + (size_t)o * H + r0w);
  f32x2 psynv, htv;
  #pragma unroll
  for (int i = 0; i < 2; ++i) {
    wzv[i] *= wzm[i];
    psynv[i] = 1.0f / pv[i];
    htv[i] = 1.0f / (1.0f + __expf(-8.0f * (hv[i] - 0.5f)));
  }

  const float INV_TAU = 1.0f / 0.01f, INV_TD = 1.0f / 0.2f, INV_TF = 1.0f / 1.5f;

  // packed-s publish address: 2 consecutive u32 (j = r0w, r0w+1, batch bo)
  unsigned int* pubp = sbuf + (((r0w >> 3) << 7) + (bo << 3) + (r0w & 7));

#define WAITV(n) { asm volatile("s_waitcnt vmcnt(" #n ")" ::: "memory"); \
                   __builtin_amdgcn_sched_barrier(0); }

  // ---- publish s_0 (tagged dwordx2, fire-and-forget) ----
  {
    u32x2 pk;
    #pragma unroll
    for (int i = 0; i < 2; ++i)
      pk[i] = (pack_split(htv[i] * rv[i] * uv[i] * psynv[i]) & ~1u) | TAG(0);
    asm volatile("global_store_dwordx2 %0, %1, off sc0 sc1" :: "v"(pubp), "v"(pk) : "memory");
  }

  float* ph = dout + H_OFF + (size_t)bo * (SEQ * H) + r0w;
  float* pr = dout + R_OFF + (size_t)bo * (SEQ * H) + r0w;
  float* pu = dout + U_OFF + (size_t)bo * (SEQ * H) + r0w;
  const float* ip = Irep + bo;
  float Itc = ip[0];

// chunk c: k = w*256 + c*32 + klane*8 + [0,8)
#define ISSUE_CHUNK(c) { \
    const unsigned int* ap = sb + ((w * 32 + (c) * 4 + klane) * 128 + arow * 8); \
    asm volatile("global_load_dwordx4 %0, %1, off sc0 sc1" : "=v"(ld[2*(c)])   : "v"(ap)     : "memory"); \
    asm volatile("global_load_dwordx4 %0, %1, off sc0 sc1" : "=v"(ld[2*(c)+1]) : "v"(ap + 4) : "memory"); }

#define VCHK(c, okv) { u32x4 v0 = ld[2*(c)], v1 = ld[2*(c)+1]; \
    unsigned int bad = (v0.x ^ tg) | (v0.y ^ tg) | (v0.z ^ tg) | (v0.w ^ tg) \
                     | (v1.x ^ tg) | (v1.y ^ tg) | (v1.z ^ tg) | (v1.w ^ tg); \
    okv = __all((int)((bad & 1u) == 0)); }

#define DO_CHUNK(c) { \
    u32x4 q0 = ld[2*(c)], q1 = ld[2*(c)+1]; \
    s16x8 bh, bl; \
    bh[0]=(short)(q0.x>>16); bl[0]=(short)q0.x; \
    bh[1]=(short)(q0.y>>16); bl[1]=(short)q0.y; \
    bh[2]=(short)(q0.z>>16); bl[2]=(short)q0.z; \
    bh[3]=(short)(q0.w>>16); bl[3]=(short)q0.w; \
    bh[4]=(short)(q1.x>>16); bl[4]=(short)q1.x; \
    bh[5]=(short)(q1.y>>16); bl[5]=(short)q1.y; \
    bh[6]=(short)(q1.z>>16); bl[6]=(short)q1.z; \
    bh[7]=(short)(q1.w>>16); bl[7]=(short)q1.w; \
    _Pragma("unroll") for (int rt = 0; rt < 2; ++rt) { \
      acc[rt] = __builtin_amdgcn_mfma_f32_16x16x32_bf16(ahi[rt][c], bh, acc[rt], 0, 0, 0); \
      acc[rt] = __builtin_amdgcn_mfma_f32_16x16x32_bf16(ahi[rt][c], bl, acc[rt], 0, 0, 0); \
      acc[rt] = __builtin_amdgcn_mfma_f32_16x16x32_bf16(alo[rt][c], bh, acc[rt], 0, 0, 0); \
      acc[rt] = __builtin_amdgcn_mfma_f32_16x16x32_bf16(alo[rt][c], bl, acc[rt], 0, 0, 0); } }

#define FIRST_PASS(c, n) { WAITV(n); int ok; VCHK(c, ok); \
    if (ok) { DO_CHUNK(c); done |= (1 << (c)); } }

  for (int t = 0; t < SEQ; ++t) {
    const unsigned int tg = TAG(t);
    const unsigned int* sb = sbuf + (t & 1) * (BATCH * H);

    // ---- speculative slice load; per-chunk verify -> MFMA; retry stale chunks ----
    u32x4 ld[16];
    f32x4 acc[2] = {{0.f,0.f,0.f,0.f},{0.f,0.f,0.f,0.f}};
    int done = 0;

    ISSUE_CHUNK(0) ISSUE_CHUNK(1) ISSUE_CHUNK(2) ISSUE_CHUNK(3)
    ISSUE_CHUNK(4) ISSUE_CHUNK(5) ISSUE_CHUNK(6) ISSUE_CHUNK(7)

    FIRST_PASS(0,14) FIRST_PASS(1,12) FIRST_PASS(2,10) FIRST_PASS(3,8)
    FIRST_PASS(4,6)  FIRST_PASS(5,4)  FIRST_PASS(6,2)  FIRST_PASS(7,0)

    {
      int guard = 0;
      while (done != 0xff && ++guard < (1 << 13)) {
        #pragma unroll
        for (int c = 0; c < 8; ++c)
          if (!(done & (1 << c))) ISSUE_CHUNK(c);
        WAITV(0);
        #pragma unroll
        for (int c = 0; c < 8; ++c)
          if (!(done & (1 << c))) {
            int ok; VCHK(c, ok);
            if (ok) { DO_CHUNK(c); done |= (1 << c); }
          }
      }
    }

    // ---- cross-wave K reduce (C: row = klane*4+reg, col = arow) ----
    const int pb = t & 1;
    #pragma unroll
    for (int rt = 0; rt < 2; ++rt) {
      redC[pb][w][rt][klane * 4 + 0][arow] = acc[rt][0];
      redC[pb][w][rt][klane * 4 + 1][arow] = acc[rt][1];
      redC[pb][w][rt][klane * 4 + 2][arow] = acc[rt][2];
      redC[pb][w][rt][klane * 4 + 3][arow] = acc[rt][3];
    }
    __syncthreads();

    // ---- flush previous step's z partials (zsc written before barrier at t-1) ----
    if (t > 0 && w == 0 && lane < 16) {
      const int zp = (t - 1) & 1;
      float zs = zsc[zp][0][lane] + zsc[zp][1][lane] + zsc[zp][2][lane] + zsc[zp][3][lane];
      zpart[((size_t)(t - 1) * G + g) * BATCH + lane] = zs;
    }

    // ---- reduce rec for owned rows ----
    const int rtile = w >> 1, rbase = (w & 1) * 8 + 2 * klane;
    f32x2 rec;
    #pragma unroll
    for (int i = 0; i < 2; ++i)
      rec[i] = redC[pb][0][rtile][rbase + i][arow] + redC[pb][1][rtile][rbase + i][arow]
             + redC[pb][2][rtile][rbase + i][arow] + redC[pb][3][rtile][rbase + i][arow];

    // ---- state update x2 (n == 0 identically) ----
    f32x2 hn, htn, rn, un; u32x2 pk;
    #pragma unroll
    for (int i = 0; i < 2; ++i) {
      float ext = Itc * wihv[i] + oihv[i];
      hn[i]  = hv[i] + ((-hv[i] + rec[i] + ext) * INV_TAU) * 0.001f;
      htn[i] = 1.0f / (1.0f + __expf(-8.0f * (hn[i] - 0.5f)));
      rn[i]  = rv[i] + ((1.0f - rv[i]) * INV_TD - 50.0f * uv[i] * rv[i] * htv[i]) * 0.001f;
      un[i]  = uv[i] + ((pv[i] - uv[i]) * INV_TF + 50.0f * pv[i] * (1.0f - uv[i]) * htv[i]) * 0.001f;
      pk[i]  = (pack_split(htn[i] * rn[i] * un[i] * psynv[i]) & ~1u) | TAG(t + 1);
    }

    // ---- publish s_{t+1}: one tagged dwordx2, no ack, no flags ----
    {
      unsigned int* ap = pubp + ((t + 1) & 1) * (BATCH * H);
      asm volatile("global_store_dwordx2 %0, %1, off sc0 sc1" :: "v"(ap), "v"(pk) : "memory");
    }

    // ---- outputs (off critical path) ----
    *(f32x2*)(ph + (size_t)t * H) = hn;
    *(f32x2*)(pr + (size_t)t * H) = rn;
    *(f32x2*)(pu + (size_t)t * H) = un;
    float zl = htn[0] * wzv[0] + htn[1] * wzv[1];
    zl += __shfl_xor(zl, 16); zl += __shfl_xor(zl, 32);  // sum over klane -> 8-row partial
    if (lane < 16) zsc[t & 1][w][lane] = zl;

    Itc = ip[(size_t)(t + 1) * BATCH];   // prefetch next I (pad covers t+1==SEQ)
    hv = hn; htv = htn; rv = rn; uv = un;
  }

  // ---- epilogue: flush final step's z partials ----
  __syncthreads();
  if (w == 0 && lane < 16) {
    const int zp = (SEQ - 1) & 1;
    float zs = zsc[zp][0][lane] + zsc[zp][1][lane] + zsc[zp][2][lane] + zsc[zp][3][lane];
    zpart[((size_t)(SEQ - 1) * G + g) * BATCH + lane] = zs;
  }
#undef FIRST_PASS
#undef DO_CHUNK
#undef VCHK
#undef ISSUE_CHUNK
#undef WAITV
}

__global__ void zred_kernel(const float* __restrict__ zpart, const float* __restrict__ offhz,
                            float* __restrict__ zout) {
  int tid = blockIdx.x * blockDim.x + threadIdx.x;
  if (tid >= BATCH * SEQ * NOUT) return;
  int b = tid / (SEQ * NOUT);
  int rem = tid - b * (SEQ * NOUT);
  int t = rem >> 3, o = rem & 7;
  float acc = offhz[o];
  #pragma unroll
  for (int k = 0; k < 4; ++k)    // output o <- WGs 4o..4o+3 (32 rows each)
    acc += zpart[((size_t)t * G + o * 4 + k) * BATCH + b];
  zout[tid] = acc;
}

extern "C" void kernel_launch(void* const* d_in, const int* in_sizes, int n_in,
                              void* d_out, int out_size, void* d_ws, size_t ws_size,
                              hipStream_t stream) {
  const float* I     = (const float*)d_in[0];
  const float* h0    = (const float*)d_in[1];
  const float* r0    = (const float*)d_in[2];
  const float* u0    = (const float*)d_in[3];
  const float* Wih   = (const float*)d_in[4];
  const float* offih = (const float*)d_in[5];
  const float* Whh   = (const float*)d_in[6];
  const float* Whz   = (const float*)d_in[7];
  const float* offhz = (const float*)d_in[8];
  const float* prel  = (const float*)d_in[9];
  const float* Whhm  = (const float*)d_in[10];
  const float* Whzm  = (const float*)d_in[11];
  float* out = (float*)d_out;

  unsigned int* sbuf  = (unsigned int*)((char*)d_ws + SBUF_OFF);
  float* Irep  = (float*)((char*)d_ws + IREP_OFF);
  float* zpart = (float*)((char*)d_ws + ZPART_OFF);

  hipMemsetAsync(d_out, 0, (size_t)H_OFF * sizeof(float), stream);  // n_all == 0
  init_kernel<<<128, 256, 0, stream>>>(I, Irep, sbuf);
  rnn_persist<<<G, TPB, 0, stream>>>(h0, r0, u0, Wih, offih, Whh, Whz, prel, Whhm, Whzm,
                                     Irep, sbuf, zpart, out);
  zred_kernel<<<(BATCH * SEQ * NOUT + 255) / 256, 256, 0, stream>>>(zpart, offhz, out + Z_OFF);
}

// Round 12
// 4425.440 us; speedup vs baseline: 1.1218x; 1.1218x over previous
//
#include <hip/hip_runtime.h>
#include <cstdint>
#include <cstddef>

typedef float f32x4 __attribute__((ext_vector_type(4)));
typedef unsigned int u32x4 __attribute__((ext_vector_type(4)));
typedef short s16x8 __attribute__((ext_vector_type(8)));

#define H     1024
#define BATCH 16
#define SEQ   2000
#define NOUT  8
#define G     64       // persistent workgroups, 16 rows each
#define RPW   16
#define TPB   256

// d_out offsets (floats): n_all, h_all, r_all, u_all, z_all
#define H_OFF 32768000
#define R_OFF 65536000
#define U_OFF 98304000
#define Z_OFF 131072000

// ws layout (bytes)
#define SBUF_OFF  8192       // double-buffered packed s: 2*16384 u32, layout [j>>3][b][j&7]
#define IREP_OFF  139264     // I repacked [t][b] (+pad)
#define ZPART_OFF 267392     // zpart [t][g][b]

#define TAG(tau) ((unsigned int)(((tau) >> 1) & 1))

__global__ void init_kernel(const float* __restrict__ I, float* __restrict__ Irep,
                            unsigned int* __restrict__ sbuf) {
  int tid = blockIdx.x * blockDim.x + threadIdx.x;
  if (tid < SEQ * BATCH) {
    int t = tid >> 4, b = tid & 15;
    Irep[tid] = I[b * SEQ + t];            // I is [B, SEQ, 1]
  }
  if (tid < 2 * BATCH * H) {               // pre-tag both buffers stale (tag=1; s_0/s_1 expect 0)
    unsigned int* ap = sbuf + tid; unsigned int v = 1u;
    asm volatile("global_store_dword %0, %1, off sc0 sc1" :: "v"(ap), "v"(v) : "memory");
  }
}

// split f into truncated-bf16 hi + truncated-bf16 lo, packed (hi<<16)|lo
__device__ __forceinline__ unsigned int pack_split(float f) {
  unsigned int uh = __float_as_uint(f) & 0xffff0000u;
  float fl = f - __uint_as_float(uh);
  return uh | (__float_as_uint(fl) >> 16);
}

__global__ __launch_bounds__(TPB, 1) void rnn_persist(
    const float* __restrict__ h0, const float* __restrict__ r0, const float* __restrict__ u0,
    const float* __restrict__ Wih, const float* __restrict__ offih,
    const float* __restrict__ Whh, const float* __restrict__ Whz,
    const float* __restrict__ prel, const float* __restrict__ Whhm, const float* __restrict__ Whzm,
    const float* __restrict__ Irep, unsigned int* __restrict__ sbuf,
    float* __restrict__ zpart, float* __restrict__ dout)
{
  __shared__ float redC[2][4][16][17];   // [parity][wave][row][batch(+pad)]

  const int g = blockIdx.x, tid = threadIdx.x;
  const int lane = tid & 63, w = tid >> 6;
  const int arow  = lane & 15;           // MFMA A row / B col (batch)
  const int klane = lane >> 4;           // 0..3: k-subgroup
  const int ro = lane >> 2, bo = (w << 2) + (lane & 3);   // owned state (row, batch)
  const int row = g * RPW + ro;

  // ---- one-time: masked W_hh -> split-bf16 fragments in VGPRs (64 regs) ----
  s16x8 ahi[8], alo[8];
  {
    const float* wr = Whh  + (size_t)(g * RPW + arow) * H;
    const float* mr = Whhm + (size_t)(g * RPW + arow) * H;
    #pragma unroll
    for (int c = 0; c < 8; ++c) {
      const int jb = w * 256 + c * 32 + klane * 8;
      f32x4 w0 = *(const f32x4*)(wr + jb),     m0 = *(const f32x4*)(mr + jb);
      f32x4 w1 = *(const f32x4*)(wr + jb + 4), m1 = *(const f32x4*)(mr + jb + 4);
      float wf[8] = { w0.x*m0.x, w0.y*m0.y, w0.z*m0.z, w0.w*m0.w,
                      w1.x*m1.x, w1.y*m1.y, w1.z*m1.z, w1.w*m1.w };
      #pragma unroll
      for (int i = 0; i < 8; ++i) {
        unsigned int uh = __float_as_uint(wf[i]) & 0xffff0000u;
        float fl = wf[i] - __uint_as_float(uh);
        ahi[c][i] = (short)(uh >> 16);
        alo[c][i] = (short)(__float_as_uint(fl) >> 16);
      }
    }
  }

  // ---- per-lane persistent state ----
  const int sidx = bo * H + row;
  float h  = h0[sidx], rr_ = r0[sidx], u = u0[sidx];
  float p  = prel[row], psyn = 1.0f / p;
  float wih = Wih[row], oih = offih[row];
  float wz = Whz[(row >> 7) * H + row] * Whzm[(row >> 7) * H + row];
  float ht = 1.0f / (1.0f + __expf(-8.0f * (h - 0.5f)));

  const float INV_TAU = 1.0f / 0.01f, INV_TD = 1.0f / 0.2f, INV_TF = 1.0f / 1.5f;
  const int sidx3 = ((row >> 3) << 7) + (bo << 3) + (row & 7);  // [j>>3][b][j&7]

#define WAITV(n) { asm volatile("s_waitcnt vmcnt(" #n ")" ::: "memory"); \
                   __builtin_amdgcn_sched_barrier(0); }

  // ---- publish s_0 (tagged, fire-and-forget) ----
  {
    unsigned int pk = (pack_split(ht * rr_ * u * psyn) & ~1u) | TAG(0);
    unsigned int* ap = sbuf + sidx3;
    asm volatile("global_store_dword %0, %1, off sc0 sc1" :: "v"(ap), "v"(pk) : "memory");
  }

  float* ph = dout + H_OFF + (size_t)bo * (SEQ * H) + row;
  float* pr = dout + R_OFF + (size_t)bo * (SEQ * H) + row;
  float* pu = dout + U_OFF + (size_t)bo * (SEQ * H) + row;
  float* pz = zpart + (size_t)g * BATCH + (w << 2) + lane;  // valid when lane < 4
  const float* ip = Irep + bo;
  float Itc = ip[0];

// chunk c covers k = c*32 + klane*8 + [0,8); depends on source WGs 16w+2c, 16w+2c+1
#define ISSUE_CHUNK(c) { \
    const unsigned int* ap = sb + ((w * 32 + (c) * 4 + klane) * 128 + arow * 8); \
    asm volatile("global_load_dwordx4 %0, %1, off sc0 sc1" : "=v"(ld[2*(c)])   : "v"(ap)     : "memory"); \
    asm volatile("global_load_dwordx4 %0, %1, off sc0 sc1" : "=v"(ld[2*(c)+1]) : "v"(ap + 4) : "memory"); }

#define VCHK(c, okv) { u32x4 v0 = ld[2*(c)], v1 = ld[2*(c)+1]; \
    unsigned int bad = (v0.x ^ tg) | (v0.y ^ tg) | (v0.z ^ tg) | (v0.w ^ tg) \
                     | (v1.x ^ tg) | (v1.y ^ tg) | (v1.z ^ tg) | (v1.w ^ tg); \
    okv = __all((int)((bad & 1u) == 0)); }

// 3-term split product: hi*hi + hi*lo + lo*hi (lo*lo ~ 2^-16 relative, dropped)
#define DO_CHUNK(c) { \
    u32x4 q0 = ld[2*(c)], q1 = ld[2*(c)+1]; \
    s16x8 bh, bl; \
    bh[0]=(short)(q0.x>>16); bl[0]=(short)q0.x; \
    bh[1]=(short)(q0.y>>16); bl[1]=(short)q0.y; \
    bh[2]=(short)(q0.z>>16); bl[2]=(short)q0.z; \
    bh[3]=(short)(q0.w>>16); bl[3]=(short)q0.w; \
    bh[4]=(short)(q1.x>>16); bl[4]=(short)q1.x; \
    bh[5]=(short)(q1.y>>16); bl[5]=(short)q1.y; \
    bh[6]=(short)(q1.z>>16); bl[6]=(short)q1.z; \
    bh[7]=(short)(q1.w>>16); bl[7]=(short)q1.w; \
    acc = __builtin_amdgcn_mfma_f32_16x16x32_bf16(ahi[c], bh, acc, 0, 0, 0); \
    acc = __builtin_amdgcn_mfma_f32_16x16x32_bf16(ahi[c], bl, acc, 0, 0, 0); \
    acc = __builtin_amdgcn_mfma_f32_16x16x32_bf16(alo[c], bh, acc, 0, 0, 0); }

#define FIRST_PASS(c, n) { WAITV(n); int ok; VCHK(c, ok); \
    if (ok) { DO_CHUNK(c); done |= (1 << (c)); } }

  for (int t = 0; t < SEQ; ++t) {
    const unsigned int tg = TAG(t);
    const unsigned int* sb = sbuf + (t & 1) * (BATCH * H);

    // ---- calibrated delay: let producers' publishes reach MALL before we
    //      sample (store-visibility ~500cyc; sample = issue + ~300cyc).
    //      Flips most first-pass fails (which cost a full ~900cyc retry
    //      round) into first-pass hits at a fixed ~320cyc cost. ----
    asm volatile("s_sleep 5" :::);

    // ---- speculative slice load; per-chunk verify -> MFMA; retry stale chunks ----
    u32x4 ld[16];
    f32x4 acc = {0.f, 0.f, 0.f, 0.f};
    int done = 0;

    ISSUE_CHUNK(0) ISSUE_CHUNK(1) ISSUE_CHUNK(2) ISSUE_CHUNK(3)
    ISSUE_CHUNK(4) ISSUE_CHUNK(5) ISSUE_CHUNK(6) ISSUE_CHUNK(7)

    FIRST_PASS(0,14) FIRST_PASS(1,12) FIRST_PASS(2,10) FIRST_PASS(3,8)
    FIRST_PASS(4,6)  FIRST_PASS(5,4)  FIRST_PASS(6,2)  FIRST_PASS(7,0)

    {
      int guard = 0;
      while (done != 0xff && ++guard < (1 << 13)) {
        #pragma unroll
        for (int c = 0; c < 8; ++c)
          if (!(done & (1 << c))) ISSUE_CHUNK(c);
        WAITV(0);
        #pragma unroll
        for (int c = 0; c < 8; ++c)
          if (!(done & (1 << c))) {
            int ok; VCHK(c, ok);
            if (ok) { DO_CHUNK(c); done |= (1 << c); }
          }
      }
    }

    // ---- cross-wave K reduce (C: row=klane*4+i, col=arow) ----
    const int pbuf = t & 1;
    redC[pbuf][w][klane * 4 + 0][arow] = acc.x;
    redC[pbuf][w][klane * 4 + 1][arow] = acc.y;
    redC[pbuf][w][klane * 4 + 2][arow] = acc.z;
    redC[pbuf][w][klane * 4 + 3][arow] = acc.w;
    __syncthreads();
    float rec = redC[pbuf][0][ro][bo] + redC[pbuf][1][ro][bo]
              + redC[pbuf][2][ro][bo] + redC[pbuf][3][ro][bo];

    // ---- state update (n == 0 identically) ----
    float ext = Itc * wih + oih;
    float hn  = h + ((-h + rec + ext) * INV_TAU) * 0.001f;
    float htn = 1.0f / (1.0f + __expf(-8.0f * (hn - 0.5f)));
    float rn  = rr_ + ((1.0f - rr_) * INV_TD - 50.0f * u * rr_ * ht) * 0.001f;
    float un  = u + ((p - u) * INV_TF + 50.0f * p * (1.0f - u) * ht) * 0.001f;

    // ---- publish s_{t+1}: tagged single store, no ack, no flags ----
    {
      unsigned int pk = (pack_split(htn * rn * un * psyn) & ~1u) | TAG(t + 1);
      unsigned int* ap = sbuf + ((t + 1) & 1) * (BATCH * H) + sidx3;
      asm volatile("global_store_dword %0, %1, off sc0 sc1" :: "v"(ap), "v"(pk) : "memory");
    }

    // ---- outputs (off critical path) ----
    ph[(size_t)t * H] = hn; pr[(size_t)t * H] = rn; pu[(size_t)t * H] = un;
    float zl = htn * wz;
    zl += __shfl_xor(zl, 4); zl += __shfl_xor(zl, 8);
    zl += __shfl_xor(zl, 16); zl += __shfl_xor(zl, 32);
    if (lane < 4) pz[(size_t)t * (G * BATCH)] = zl;

    Itc = ip[(size_t)(t + 1) * BATCH];   // prefetch next I (pad covers t+1==SEQ)
    h = hn; ht = htn; rr_ = rn; u = un;
  }
#undef FIRST_PASS
#undef DO_CHUNK
#undef VCHK
#undef ISSUE_CHUNK
#undef WAITV
}

__global__ void zred_kernel(const float* __restrict__ zpart, const float* __restrict__ offhz,
                            float* __restrict__ zout) {
  int tid = blockIdx.x * blockDim.x + threadIdx.x;
  if (tid >= BATCH * SEQ * NOUT) return;
  int b = tid / (SEQ * NOUT);
  int rem = tid - b * (SEQ * NOUT);
  int t = rem >> 3, o = rem & 7;
  float acc = offhz[o];
  #pragma unroll
  for (int k = 0; k < G / NOUT; ++k)
    acc += zpart[((size_t)t * G + o * (G / NOUT) + k) * BATCH + b];
  zout[tid] = acc;
}

extern "C" void kernel_launch(void* const* d_in, const int* in_sizes, int n_in,
                              void* d_out, int out_size, void* d_ws, size_t ws_size,
                              hipStream_t stream) {
  const float* I     = (const float*)d_in[0];
  const float* h0    = (const float*)d_in[1];
  const float* r0    = (const float*)d_in[2];
  const float* u0    = (const float*)d_in[3];
  const float* Wih   = (const float*)d_in[4];
  const float* offih = (const float*)d_in[5];
  const float* Whh   = (const float*)d_in[6];
  const float* Whz   = (const float*)d_in[7];
  const float* offhz = (const float*)d_in[8];
  const float* prel  = (const float*)d_in[9];
  const float* Whhm  = (const float*)d_in[10];
  const float* Whzm  = (const float*)d_in[11];
  float* out = (float*)d_out;

  unsigned int* sbuf  = (unsigned int*)((char*)d_ws + SBUF_OFF);
  float* Irep  = (float*)((char*)d_ws + IREP_OFF);
  float* zpart = (float*)((char*)d_ws + ZPART_OFF);

  hipMemsetAsync(d_out, 0, (size_t)H_OFF * sizeof(float), stream);  // n_all == 0
  init_kernel<<<128, 256, 0, stream>>>(I, Irep, sbuf);
  rnn_persist<<<G, TPB, 0, stream>>>(h0, r0, u0, Wih, offih, Whh, Whz, prel, Whhm, Whzm,
                                     Irep, sbuf, zpart, out);
  zred_kernel<<<(BATCH * SEQ * NOUT + 255) / 256, 256, 0, stream>>>(zpart, offhz, out + Z_OFF);
}

// Round 13
// 4097.622 us; speedup vs baseline: 1.2116x; 1.0800x over previous
//
#include <hip/hip_runtime.h>
#include <cstdint>
#include <cstddef>

typedef float f32x4 __attribute__((ext_vector_type(4)));
typedef unsigned int u32x4 __attribute__((ext_vector_type(4)));
typedef short s16x8 __attribute__((ext_vector_type(8)));

#define H     1024
#define BATCH 16
#define SEQ   2000
#define NOUT  8
#define G     64       // persistent workgroups, 16 rows each
#define RPW   16
#define TPB   256

// d_out offsets (floats): n_all, h_all, r_all, u_all, z_all
#define H_OFF 32768000
#define R_OFF 65536000
#define U_OFF 98304000
#define Z_OFF 131072000

// ws layout (bytes)
#define SBUF_OFF  8192       // double-buffered packed s: 2*16384 u32, layout [j>>3][b][j&7]
#define IREP_OFF  139264     // I repacked [t][b] (+pad)
#define ZPART_OFF 267392     // zpart [t][g][b]

#define TAG(tau) ((unsigned int)(((tau) >> 1) & 1))

__global__ void init_kernel(const float* __restrict__ I, float* __restrict__ Irep,
                            unsigned int* __restrict__ sbuf) {
  int tid = blockIdx.x * blockDim.x + threadIdx.x;
  if (tid < SEQ * BATCH) {
    int t = tid >> 4, b = tid & 15;
    Irep[tid] = I[b * SEQ + t];            // I is [B, SEQ, 1]
  }
  if (tid < 2 * BATCH * H) {               // pre-tag both buffers stale (tag=1; s_0/s_1 expect 0)
    unsigned int* ap = sbuf + tid; unsigned int v = 1u;
    asm volatile("global_store_dword %0, %1, off sc0 sc1" :: "v"(ap), "v"(v) : "memory");
  }
}

// split f into truncated-bf16 hi + truncated-bf16 lo, packed (hi<<16)|lo
__device__ __forceinline__ unsigned int pack_split(float f) {
  unsigned int uh = __float_as_uint(f) & 0xffff0000u;
  float fl = f - __uint_as_float(uh);
  return uh | (__float_as_uint(fl) >> 16);
}

__global__ __launch_bounds__(TPB, 1) void rnn_persist(
    const float* __restrict__ h0, const float* __restrict__ r0, const float* __restrict__ u0,
    const float* __restrict__ Wih, const float* __restrict__ offih,
    const float* __restrict__ Whh, const float* __restrict__ Whz,
    const float* __restrict__ prel, const float* __restrict__ Whhm, const float* __restrict__ Whzm,
    const float* __restrict__ Irep, unsigned int* __restrict__ sbuf,
    float* __restrict__ zpart, float* __restrict__ dout)
{
  __shared__ float redC[2][4][16][17];   // [parity][wave][row][batch(+pad)]

  const int g = blockIdx.x, tid = threadIdx.x;
  const int lane = tid & 63, w = tid >> 6;
  const int arow  = lane & 15;           // MFMA A row / B col (batch)
  const int klane = lane >> 4;           // 0..3: k-subgroup
  const int ro = lane >> 2, bo = (w << 2) + (lane & 3);   // owned state (row, batch)
  const int row = g * RPW + ro;

  // ---- one-time: masked W_hh -> split-bf16 fragments in VGPRs (64 regs) ----
  s16x8 ahi[8], alo[8];
  {
    const float* wr = Whh  + (size_t)(g * RPW + arow) * H;
    const float* mr = Whhm + (size_t)(g * RPW + arow) * H;
    #pragma unroll
    for (int c = 0; c < 8; ++c) {
      const int jb = w * 256 + c * 32 + klane * 8;
      f32x4 w0 = *(const f32x4*)(wr + jb),     m0 = *(const f32x4*)(mr + jb);
      f32x4 w1 = *(const f32x4*)(wr + jb + 4), m1 = *(const f32x4*)(mr + jb + 4);
      float wf[8] = { w0.x*m0.x, w0.y*m0.y, w0.z*m0.z, w0.w*m0.w,
                      w1.x*m1.x, w1.y*m1.y, w1.z*m1.z, w1.w*m1.w };
      #pragma unroll
      for (int i = 0; i < 8; ++i) {
        unsigned int uh = __float_as_uint(wf[i]) & 0xffff0000u;
        float fl = wf[i] - __uint_as_float(uh);
        ahi[c][i] = (short)(uh >> 16);
        alo[c][i] = (short)(__float_as_uint(fl) >> 16);
      }
    }
  }

  // ---- per-lane persistent state ----
  const int sidx = bo * H + row;
  float h  = h0[sidx], rr_ = r0[sidx], u = u0[sidx];
  float p  = prel[row], psyn = 1.0f / p;
  float wih = Wih[row], oih = offih[row];
  float wz = Whz[(row >> 7) * H + row] * Whzm[(row >> 7) * H + row];
  float ht = 1.0f / (1.0f + __expf(-8.0f * (h - 0.5f)));

  const float INV_TAU = 1.0f / 0.01f, INV_TD = 1.0f / 0.2f, INV_TF = 1.0f / 1.5f;
  const int sidx3 = ((row >> 3) << 7) + (bo << 3) + (row & 7);  // [j>>3][b][j&7]

#define WAITV(n) { asm volatile("s_waitcnt vmcnt(" #n ")" ::: "memory"); \
                   __builtin_amdgcn_sched_barrier(0); }

  // ---- publish s_0 (tagged, fire-and-forget) ----
  {
    unsigned int pk = (pack_split(ht * rr_ * u * psyn) & ~1u) | TAG(0);
    unsigned int* ap = sbuf + sidx3;
    asm volatile("global_store_dword %0, %1, off sc0 sc1" :: "v"(ap), "v"(pk) : "memory");
  }

  float* ph = dout + H_OFF + (size_t)bo * (SEQ * H) + row;
  float* pr = dout + R_OFF + (size_t)bo * (SEQ * H) + row;
  float* pu = dout + U_OFF + (size_t)bo * (SEQ * H) + row;
  float* pz = zpart + (size_t)g * BATCH + (w << 2) + lane;  // valid when lane < 4
  const float* ip = Irep + bo;
  float Itc = ip[0];

// chunk c covers k = c*32 + klane*8 + [0,8); depends on source WGs 16w+2c, 16w+2c+1
#define ISSUE_CHUNK(c) { \
    const unsigned int* ap = sb + ((w * 32 + (c) * 4 + klane) * 128 + arow * 8); \
    asm volatile("global_load_dwordx4 %0, %1, off sc0 sc1" : "=v"(ld[2*(c)])   : "v"(ap)     : "memory"); \
    asm volatile("global_load_dwordx4 %0, %1, off sc0 sc1" : "=v"(ld[2*(c)+1]) : "v"(ap + 4) : "memory"); }

#define VCHK(c, okv) { u32x4 v0 = ld[2*(c)], v1 = ld[2*(c)+1]; \
    unsigned int bad = (v0.x ^ tg) | (v0.y ^ tg) | (v0.z ^ tg) | (v0.w ^ tg) \
                     | (v1.x ^ tg) | (v1.y ^ tg) | (v1.z ^ tg) | (v1.w ^ tg); \
    okv = __all((int)((bad & 1u) == 0)); }

// 3-term split product: hi*hi + hi*lo + lo*hi (lo*lo ~ 2^-16 relative, dropped)
#define DO_CHUNK(c) { \
    u32x4 q0 = ld[2*(c)], q1 = ld[2*(c)+1]; \
    s16x8 bh, bl; \
    bh[0]=(short)(q0.x>>16); bl[0]=(short)q0.x; \
    bh[1]=(short)(q0.y>>16); bl[1]=(short)q0.y; \
    bh[2]=(short)(q0.z>>16); bl[2]=(short)q0.z; \
    bh[3]=(short)(q0.w>>16); bl[3]=(short)q0.w; \
    bh[4]=(short)(q1.x>>16); bl[4]=(short)q1.x; \
    bh[5]=(short)(q1.y>>16); bl[5]=(short)q1.y; \
    bh[6]=(short)(q1.z>>16); bl[6]=(short)q1.z; \
    bh[7]=(short)(q1.w>>16); bl[7]=(short)q1.w; \
    acc = __builtin_amdgcn_mfma_f32_16x16x32_bf16(ahi[c], bh, acc, 0, 0, 0); \
    acc = __builtin_amdgcn_mfma_f32_16x16x32_bf16(ahi[c], bl, acc, 0, 0, 0); \
    acc = __builtin_amdgcn_mfma_f32_16x16x32_bf16(alo[c], bh, acc, 0, 0, 0); }

#define FIRST_PASS(c, n) { WAITV(n); int ok; VCHK(c, ok); \
    if (ok) { DO_CHUNK(c); done |= (1 << (c)); } }

  for (int t = 0; t < SEQ; ++t) {
    const unsigned int tg = TAG(t);
    const unsigned int* sb = sbuf + (t & 1) * (BATCH * H);

    // ---- adaptive delay: wait until our own publish (and output stores)
    //      have retired at the fabric. All WGs are lockstep, so own-store-
    //      retired is a calibrated, congestion-adaptive proxy for peer
    //      stores being visible -> first-pass hit rate ~1. ----
    WAITV(0);

    // ---- speculative slice load; per-chunk verify -> MFMA; retry stale chunks ----
    u32x4 ld[16];
    f32x4 acc = {0.f, 0.f, 0.f, 0.f};
    int done = 0;

    ISSUE_CHUNK(0) ISSUE_CHUNK(1) ISSUE_CHUNK(2) ISSUE_CHUNK(3)
    ISSUE_CHUNK(4) ISSUE_CHUNK(5) ISSUE_CHUNK(6) ISSUE_CHUNK(7)

    FIRST_PASS(0,14) FIRST_PASS(1,12) FIRST_PASS(2,10) FIRST_PASS(3,8)
    FIRST_PASS(4,6)  FIRST_PASS(5,4)  FIRST_PASS(6,2)  FIRST_PASS(7,0)

    {
      int guard = 0;
      while (done != 0xff && ++guard < (1 << 13)) {
        #pragma unroll
        for (int c = 0; c < 8; ++c)
          if (!(done & (1 << c))) ISSUE_CHUNK(c);
        WAITV(0);
        #pragma unroll
        for (int c = 0; c < 8; ++c)
          if (!(done & (1 << c))) {
            int ok; VCHK(c, ok);
            if (ok) { DO_CHUNK(c); done |= (1 << c); }
          }
      }
    }

    // ---- cross-wave K reduce (C: row=klane*4+i, col=arow) ----
    const int pbuf = t & 1;
    redC[pbuf][w][klane * 4 + 0][arow] = acc.x;
    redC[pbuf][w][klane * 4 + 1][arow] = acc.y;
    redC[pbuf][w][klane * 4 + 2][arow] = acc.z;
    redC[pbuf][w][klane * 4 + 3][arow] = acc.w;
    __syncthreads();
    float rec = redC[pbuf][0][ro][bo] + redC[pbuf][1][ro][bo]
              + redC[pbuf][2][ro][bo] + redC[pbuf][3][ro][bo];

    // ---- state update (n == 0 identically) ----
    float ext = Itc * wih + oih;
    float hn  = h + ((-h + rec + ext) * INV_TAU) * 0.001f;
    float htn = 1.0f / (1.0f + __expf(-8.0f * (hn - 0.5f)));
    float rn  = rr_ + ((1.0f - rr_) * INV_TD - 50.0f * u * rr_ * ht) * 0.001f;
    float un  = u + ((p - u) * INV_TF + 50.0f * p * (1.0f - u) * ht) * 0.001f;

    // ---- publish s_{t+1}: tagged single store, no ack, no flags ----
    {
      unsigned int pk = (pack_split(htn * rn * un * psyn) & ~1u) | TAG(t + 1);
      unsigned int* ap = sbuf + ((t + 1) & 1) * (BATCH * H) + sidx3;
      asm volatile("global_store_dword %0, %1, off sc0 sc1" :: "v"(ap), "v"(pk) : "memory");
    }

    // ---- outputs (off critical path; drained by next step's head WAITV) ----
    ph[(size_t)t * H] = hn; pr[(size_t)t * H] = rn; pu[(size_t)t * H] = un;
    float zl = htn * wz;
    zl += __shfl_xor(zl, 4); zl += __shfl_xor(zl, 8);
    zl += __shfl_xor(zl, 16); zl += __shfl_xor(zl, 32);
    if (lane < 4) pz[(size_t)t * (G * BATCH)] = zl;

    Itc = ip[(size_t)(t + 1) * BATCH];   // prefetch next I (pad covers t+1==SEQ)
    h = hn; ht = htn; rr_ = rn; u = un;
  }
#undef FIRST_PASS
#undef DO_CHUNK
#undef VCHK
#undef ISSUE_CHUNK
#undef WAITV
}

__global__ void zred_kernel(const float* __restrict__ zpart, const float* __restrict__ offhz,
                            float* __restrict__ zout) {
  int tid = blockIdx.x * blockDim.x + threadIdx.x;
  if (tid >= BATCH * SEQ * NOUT) return;
  int b = tid / (SEQ * NOUT);
  int rem = tid - b * (SEQ * NOUT);
  int t = rem >> 3, o = rem & 7;
  float acc = offhz[o];
  #pragma unroll
  for (int k = 0; k < G / NOUT; ++k)
    acc += zpart[((size_t)t * G + o * (G / NOUT) + k) * BATCH + b];
  zout[tid] = acc;
}

extern "C" void kernel_launch(void* const* d_in, const int* in_sizes, int n_in,
                              void* d_out, int out_size, void* d_ws, size_t ws_size,
                              hipStream_t stream) {
  const float* I     = (const float*)d_in[0];
  const float* h0    = (const float*)d_in[1];
  const float* r0    = (const float*)d_in[2];
  const float* u0    = (const float*)d_in[3];
  const float* Wih   = (const float*)d_in[4];
  const float* offih = (const float*)d_in[5];
  const float* Whh   = (const float*)d_in[6];
  const float* Whz   = (const float*)d_in[7];
  const float* offhz = (const float*)d_in[8];
  const float* prel  = (const float*)d_in[9];
  const float* Whhm  = (const float*)d_in[10];
  const float* Whzm  = (const float*)d_in[11];
  float* out = (float*)d_out;

  unsigned int* sbuf  = (unsigned int*)((char*)d_ws + SBUF_OFF);
  float* Irep  = (float*)((char*)d_ws + IREP_OFF);
  float* zpart = (float*)((char*)d_ws + ZPART_OFF);

  hipMemsetAsync(d_out, 0, (size_t)H_OFF * sizeof(float), stream);  // n_all == 0
  init_kernel<<<128, 256, 0, stream>>>(I, Irep, sbuf);
  rnn_persist<<<G, TPB, 0, stream>>>(h0, r0, u0, Wih, offih, Whh, Whz, prel, Whhm, Whzm,
                                     Irep, sbuf, zpart, out);
  zred_kernel<<<(BATCH * SEQ * NOUT + 255) / 256, 256, 0, stream>>>(zpart, offhz, out + Z_OFF);
}

// Round 14
// 4061.209 us; speedup vs baseline: 1.2224x; 1.0090x over previous
//
#include <hip/hip_runtime.h>
#include <cstdint>
#include <cstddef>

typedef float f32x4 __attribute__((ext_vector_type(4)));
typedef unsigned int u32x4 __attribute__((ext_vector_type(4)));
typedef short s16x8 __attribute__((ext_vector_type(8)));

#define H     1024
#define BATCH 16
#define SEQ   2000
#define NOUT  8
#define G     64       // persistent workgroups, 16 rows each
#define RPW   16
#define TPB   256

// d_out offsets (floats): n_all, h_all, r_all, u_all, z_all
#define H_OFF 32768000
#define R_OFF 65536000
#define U_OFF 98304000
#define Z_OFF 131072000

// ws layout (bytes)
#define SBUF_OFF  8192       // double-buffered packed s: 2*16384 u32, layout [j>>3][b][j&7]
#define IREP_OFF  139264     // I repacked [t][b] (+pad)
#define ZPART_OFF 267392     // zpart [t][g][b]

#define TAG(tau) ((unsigned int)(((tau) >> 1) & 1))

__global__ void init_kernel(const float* __restrict__ I, float* __restrict__ Irep,
                            unsigned int* __restrict__ sbuf) {
  int tid = blockIdx.x * blockDim.x + threadIdx.x;
  if (tid < SEQ * BATCH) {
    int t = tid >> 4, b = tid & 15;
    Irep[tid] = I[b * SEQ + t];            // I is [B, SEQ, 1]
  }
  if (tid < 2 * BATCH * H) {               // pre-tag both buffers stale (tag=1; s_0/s_1 expect 0)
    unsigned int* ap = sbuf + tid; unsigned int v = 1u;
    asm volatile("global_store_dword %0, %1, off sc0 sc1" :: "v"(ap), "v"(v) : "memory");
  }
}

// split f into truncated-bf16 hi + truncated-bf16 lo, packed (hi<<16)|lo
__device__ __forceinline__ unsigned int pack_split(float f) {
  unsigned int uh = __float_as_uint(f) & 0xffff0000u;
  float fl = f - __uint_as_float(uh);
  return uh | (__float_as_uint(fl) >> 16);
}

__global__ __launch_bounds__(TPB, 1) void rnn_persist(
    const float* __restrict__ h0, const float* __restrict__ r0, const float* __restrict__ u0,
    const float* __restrict__ Wih, const float* __restrict__ offih,
    const float* __restrict__ Whh, const float* __restrict__ Whz,
    const float* __restrict__ prel, const float* __restrict__ Whhm, const float* __restrict__ Whzm,
    const float* __restrict__ Irep, unsigned int* __restrict__ sbuf,
    float* __restrict__ zpart, float* __restrict__ dout)
{
  __shared__ float redC[2][4][16][17];   // [parity][wave][row][batch(+pad)]

  const int g = blockIdx.x, tid = threadIdx.x;
  const int lane = tid & 63, w = tid >> 6;
  const int arow  = lane & 15;           // MFMA A row / B col (batch)  [fragment role]
  const int klane = lane >> 4;           // 0..3: k-subgroup            [fragment role]
  // state-ownership map (coalesced publish): row varies fastest across lanes
  const int ro = lane & 15;              // owned row within WG
  const int bo = (w << 2) + (lane >> 4); // owned batch
  const int row = g * RPW + ro;

  // ---- one-time: masked W_hh -> split-bf16 fragments in VGPRs (64 regs) ----
  s16x8 ahi[8], alo[8];
  {
    const float* wr = Whh  + (size_t)(g * RPW + arow) * H;
    const float* mr = Whhm + (size_t)(g * RPW + arow) * H;
    #pragma unroll
    for (int c = 0; c < 8; ++c) {
      const int jb = w * 256 + c * 32 + klane * 8;
      f32x4 w0 = *(const f32x4*)(wr + jb),     m0 = *(const f32x4*)(mr + jb);
      f32x4 w1 = *(const f32x4*)(wr + jb + 4), m1 = *(const f32x4*)(mr + jb + 4);
      float wf[8] = { w0.x*m0.x, w0.y*m0.y, w0.z*m0.z, w0.w*m0.w,
                      w1.x*m1.x, w1.y*m1.y, w1.z*m1.z, w1.w*m1.w };
      #pragma unroll
      for (int i = 0; i < 8; ++i) {
        unsigned int uh = __float_as_uint(wf[i]) & 0xffff0000u;
        float fl = wf[i] - __uint_as_float(uh);
        ahi[c][i] = (short)(uh >> 16);
        alo[c][i] = (short)(__float_as_uint(fl) >> 16);
      }
    }
  }

  // ---- per-lane persistent state ----
  const int sidx = bo * H + row;
  float h  = h0[sidx], rr_ = r0[sidx], u = u0[sidx];
  float p  = prel[row], psyn = 1.0f / p;
  float wih = Wih[row], oih = offih[row];
  float wz = Whz[(row >> 7) * H + row] * Whzm[(row >> 7) * H + row];
  float ht = 1.0f / (1.0f + __expf(-8.0f * (h - 0.5f)));

  const float INV_TAU = 1.0f / 0.01f, INV_TD = 1.0f / 0.2f, INV_TF = 1.0f / 1.5f;
  // publish addr: lanes 0-7 contiguous, 8-lane runs -> 4 lines/wave (was 32)
  const int sidx3 = ((row >> 3) << 7) + (bo << 3) + (row & 7);  // [j>>3][b][j&7]

#define WAITV(n) { asm volatile("s_waitcnt vmcnt(" #n ")" ::: "memory"); \
                   __builtin_amdgcn_sched_barrier(0); }

  // ---- publish s_0 (tagged, fire-and-forget) ----
  {
    unsigned int pk = (pack_split(ht * rr_ * u * psyn) & ~1u) | TAG(0);
    unsigned int* ap = sbuf + sidx3;
    asm volatile("global_store_dword %0, %1, off sc0 sc1" :: "v"(ap), "v"(pk) : "memory");
  }

  float* ph = dout + H_OFF + (size_t)bo * (SEQ * H) + row;
  float* pr = dout + R_OFF + (size_t)bo * (SEQ * H) + row;
  float* pu = dout + U_OFF + (size_t)bo * (SEQ * H) + row;
  // z writer lanes: (lane&15)==0 -> 4 lanes/wave, consecutive zpart dwords
  float* pz = zpart + (size_t)g * BATCH + (w << 2) + (lane >> 4);
  const float* ip = Irep + bo;
  float Itc = ip[0];

// chunk c covers k = c*32 + klane*8 + [0,8); depends on source WGs 16w+2c, 16w+2c+1
#define ISSUE_CHUNK(c) { \
    const unsigned int* ap = sb + ((w * 32 + (c) * 4 + klane) * 128 + arow * 8); \
    asm volatile("global_load_dwordx4 %0, %1, off sc0 sc1" : "=v"(ld[2*(c)])   : "v"(ap)     : "memory"); \
    asm volatile("global_load_dwordx4 %0, %1, off sc0 sc1" : "=v"(ld[2*(c)+1]) : "v"(ap + 4) : "memory"); }

#define VCHK(c, okv) { u32x4 v0 = ld[2*(c)], v1 = ld[2*(c)+1]; \
    unsigned int bad = (v0.x ^ tg) | (v0.y ^ tg) | (v0.z ^ tg) | (v0.w ^ tg) \
                     | (v1.x ^ tg) | (v1.y ^ tg) | (v1.z ^ tg) | (v1.w ^ tg); \
    okv = __all((int)((bad & 1u) == 0)); }

// 3-term split product: hi*hi + hi*lo + lo*hi (lo*lo ~ 2^-16 relative, dropped)
#define DO_CHUNK(c) { \
    u32x4 q0 = ld[2*(c)], q1 = ld[2*(c)+1]; \
    s16x8 bh, bl; \
    bh[0]=(short)(q0.x>>16); bl[0]=(short)q0.x; \
    bh[1]=(short)(q0.y>>16); bl[1]=(short)q0.y; \
    bh[2]=(short)(q0.z>>16); bl[2]=(short)q0.z; \
    bh[3]=(short)(q0.w>>16); bl[3]=(short)q0.w; \
    bh[4]=(short)(q1.x>>16); bl[4]=(short)q1.x; \
    bh[5]=(short)(q1.y>>16); bl[5]=(short)q1.y; \
    bh[6]=(short)(q1.z>>16); bl[6]=(short)q1.z; \
    bh[7]=(short)(q1.w>>16); bl[7]=(short)q1.w; \
    acc = __builtin_amdgcn_mfma_f32_16x16x32_bf16(ahi[c], bh, acc, 0, 0, 0); \
    acc = __builtin_amdgcn_mfma_f32_16x16x32_bf16(ahi[c], bl, acc, 0, 0, 0); \
    acc = __builtin_amdgcn_mfma_f32_16x16x32_bf16(alo[c], bh, acc, 0, 0, 0); }

#define FIRST_PASS(c, n) { WAITV(n); int ok; VCHK(c, ok); \
    if (ok) { DO_CHUNK(c); done |= (1 << (c)); } }

  for (int t = 0; t < SEQ; ++t) {
    const unsigned int tg = TAG(t);
    const unsigned int* sb = sbuf + (t & 1) * (BATCH * H);

    // ---- adaptive delay: wait until our own PUBLISH has retired (in-order
    //      vmcnt: 5 newer tail ops — 3 outputs, zpart, I-load — may remain
    //      in flight). Own-publish-retired is a congestion-adaptive proxy
    //      for peer publishes being visible. ----
    WAITV(5);

    // ---- speculative slice load; per-chunk verify -> MFMA; retry stale chunks ----
    u32x4 ld[16];
    f32x4 acc = {0.f, 0.f, 0.f, 0.f};
    int done = 0;

    ISSUE_CHUNK(0) ISSUE_CHUNK(1) ISSUE_CHUNK(2) ISSUE_CHUNK(3)
    ISSUE_CHUNK(4) ISSUE_CHUNK(5) ISSUE_CHUNK(6) ISSUE_CHUNK(7)

    // counts unchanged: the <=5 older tail ops retire before these loads
    FIRST_PASS(0,14) FIRST_PASS(1,12) FIRST_PASS(2,10) FIRST_PASS(3,8)
    FIRST_PASS(4,6)  FIRST_PASS(5,4)  FIRST_PASS(6,2)  FIRST_PASS(7,0)

    {
      int guard = 0;
      while (done != 0xff && ++guard < (1 << 13)) {
        #pragma unroll
        for (int c = 0; c < 8; ++c)
          if (!(done & (1 << c))) ISSUE_CHUNK(c);
        WAITV(0);
        #pragma unroll
        for (int c = 0; c < 8; ++c)
          if (!(done & (1 << c))) {
            int ok; VCHK(c, ok);
            if (ok) { DO_CHUNK(c); done |= (1 << c); }
          }
      }
    }

    // ---- cross-wave K reduce (C: row=klane*4+i, col=arow) ----
    const int pbuf = t & 1;
    redC[pbuf][w][klane * 4 + 0][arow] = acc.x;
    redC[pbuf][w][klane * 4 + 1][arow] = acc.y;
    redC[pbuf][w][klane * 4 + 2][arow] = acc.z;
    redC[pbuf][w][klane * 4 + 3][arow] = acc.w;
    __syncthreads();
    float rec = redC[pbuf][0][ro][bo] + redC[pbuf][1][ro][bo]
              + redC[pbuf][2][ro][bo] + redC[pbuf][3][ro][bo];

    // ---- state update (n == 0 identically) ----
    float ext = Itc * wih + oih;
    float hn  = h + ((-h + rec + ext) * INV_TAU) * 0.001f;
    float htn = 1.0f / (1.0f + __expf(-8.0f * (hn - 0.5f)));
    float rn  = rr_ + ((1.0f - rr_) * INV_TD - 50.0f * u * rr_ * ht) * 0.001f;
    float un  = u + ((p - u) * INV_TF + 50.0f * p * (1.0f - u) * ht) * 0.001f;

    // ---- publish s_{t+1}: tagged single store (coalesced runs), no ack ----
    {
      unsigned int pk = (pack_split(htn * rn * un * psyn) & ~1u) | TAG(t + 1);
      unsigned int* ap = sbuf + ((t + 1) & 1) * (BATCH * H) + sidx3;
      asm volatile("global_store_dword %0, %1, off sc0 sc1" :: "v"(ap), "v"(pk) : "memory");
    }

    // ---- outputs (off critical path; not waited by next head WAITV(5)) ----
    ph[(size_t)t * H] = hn; pr[(size_t)t * H] = rn; pu[(size_t)t * H] = un;
    float zl = htn * wz;
    zl += __shfl_xor(zl, 1); zl += __shfl_xor(zl, 2);
    zl += __shfl_xor(zl, 4); zl += __shfl_xor(zl, 8);   // sum over 16 rows (same bo)
    if ((lane & 15) == 0) pz[(size_t)t * (G * BATCH)] = zl;

    Itc = ip[(size_t)(t + 1) * BATCH];   // prefetch next I (pad covers t+1==SEQ)
    h = hn; ht = htn; rr_ = rn; u = un;
  }
#undef FIRST_PASS
#undef DO_CHUNK
#undef VCHK
#undef ISSUE_CHUNK
#undef WAITV
}

__global__ void zred_kernel(const float* __restrict__ zpart, const float* __restrict__ offhz,
                            float* __restrict__ zout) {
  int tid = blockIdx.x * blockDim.x + threadIdx.x;
  if (tid >= BATCH * SEQ * NOUT) return;
  int b = tid / (SEQ * NOUT);
  int rem = tid - b * (SEQ * NOUT);
  int t = rem >> 3, o = rem & 7;
  float acc = offhz[o];
  #pragma unroll
  for (int k = 0; k < G / NOUT; ++k)
    acc += zpart[((size_t)t * G + o * (G / NOUT) + k) * BATCH + b];
  zout[tid] = acc;
}

extern "C" void kernel_launch(void* const* d_in, const int* in_sizes, int n_in,
                              void* d_out, int out_size, void* d_ws, size_t ws_size,
                              hipStream_t stream) {
  const float* I     = (const float*)d_in[0];
  const float* h0    = (const float*)d_in[1];
  const float* r0    = (const float*)d_in[2];
  const float* u0    = (const float*)d_in[3];
  const float* Wih   = (const float*)d_in[4];
  const float* offih = (const float*)d_in[5];
  const float* Whh   = (const float*)d_in[6];
  const float* Whz   = (const float*)d_in[7];
  const float* offhz = (const float*)d_in[8];
  const float* prel  = (const float*)d_in[9];
  const float* Whhm  = (const float*)d_in[10];
  const float* Whzm  = (const float*)d_in[11];
  float* out = (float*)d_out;

  unsigned int* sbuf  = (unsigned int*)((char*)d_ws + SBUF_OFF);
  float* Irep  = (float*)((char*)d_ws + IREP_OFF);
  float* zpart = (float*)((char*)d_ws + ZPART_OFF);

  hipMemsetAsync(d_out, 0, (size_t)H_OFF * sizeof(float), stream);  // n_all == 0
  init_kernel<<<128, 256, 0, stream>>>(I, Irep, sbuf);
  rnn_persist<<<G, TPB, 0, stream>>>(h0, r0, u0, Wih, offih, Whh, Whz, prel, Whhm, Whzm,
                                     Irep, sbuf, zpart, out);
  zred_kernel<<<(BATCH * SEQ * NOUT + 255) / 256, 256, 0, stream>>>(zpart, offhz, out + Z_OFF);
}

// Round 15
// 3969.976 us; speedup vs baseline: 1.2505x; 1.0230x over previous
//
#include <hip/hip_runtime.h>
#include <cstdint>
#include <cstddef>

typedef float f32x4 __attribute__((ext_vector_type(4)));
typedef unsigned int u32x4 __attribute__((ext_vector_type(4)));
typedef short s16x8 __attribute__((ext_vector_type(8)));

#define H     1024
#define BATCH 16
#define SEQ   2000
#define NOUT  8
#define G     64       // persistent workgroups, 16 rows each
#define RPW   16
#define TPB   256

// d_out offsets (floats): n_all, h_all, r_all, u_all, z_all
#define H_OFF 32768000
#define R_OFF 65536000
#define U_OFF 98304000
#define Z_OFF 131072000

// ws layout (bytes)
#define SBUF_OFF  8192       // double-buffered packed s: 2*16384 u32, layout [j>>3][b][j&7]
#define IREP_OFF  139264     // I repacked [t][b] (+pad)
#define ZPART_OFF 267392     // zpart [t][g][b]

#define TAG(tau) ((unsigned int)(((tau) >> 1) & 1))

__global__ void init_kernel(const float* __restrict__ I, float* __restrict__ Irep,
                            unsigned int* __restrict__ sbuf) {
  int tid = blockIdx.x * blockDim.x + threadIdx.x;
  if (tid < SEQ * BATCH) {
    int t = tid >> 4, b = tid & 15;
    Irep[tid] = I[b * SEQ + t];            // I is [B, SEQ, 1]
  }
  if (tid < 2 * BATCH * H) {               // pre-tag both buffers stale (tag=1; s_0/s_1 expect 0)
    unsigned int* ap = sbuf + tid; unsigned int v = 1u;
    asm volatile("global_store_dword %0, %1, off sc0 sc1" :: "v"(ap), "v"(v) : "memory");
  }
}

// split f into truncated-bf16 hi + truncated-bf16 lo, packed (hi<<16)|lo
__device__ __forceinline__ unsigned int pack_split(float f) {
  unsigned int uh = __float_as_uint(f) & 0xffff0000u;
  float fl = f - __uint_as_float(uh);
  return uh | (__float_as_uint(fl) >> 16);
}

__global__ __launch_bounds__(TPB, 1) void rnn_persist(
    const float* __restrict__ h0, const float* __restrict__ r0, const float* __restrict__ u0,
    const float* __restrict__ Wih, const float* __restrict__ offih,
    const float* __restrict__ Whh, const float* __restrict__ Whz,
    const float* __restrict__ prel, const float* __restrict__ Whhm, const float* __restrict__ Whzm,
    const float* __restrict__ Irep, unsigned int* __restrict__ sbuf,
    float* __restrict__ zpart, float* __restrict__ dout)
{
  __shared__ float redC[2][4][16][17];   // [parity][wave][row][batch(+pad)]

  const int g = blockIdx.x, tid = threadIdx.x;
  const int lane = tid & 63, w = tid >> 6;
  const int arow  = lane & 15;           // MFMA A row / B col (batch)  [fragment role]
  const int klane = lane >> 4;           // 0..3: k-subgroup            [fragment role]
  // state-ownership map (coalesced publish): row varies fastest across lanes
  const int ro = lane & 15;              // owned row within WG
  const int bo = (w << 2) + (lane >> 4); // owned batch
  const int row = g * RPW + ro;

  // ---- one-time: masked W_hh -> split-bf16 fragments in VGPRs (64 regs) ----
  s16x8 ahi[8], alo[8];
  {
    const float* wr = Whh  + (size_t)(g * RPW + arow) * H;
    const float* mr = Whhm + (size_t)(g * RPW + arow) * H;
    #pragma unroll
    for (int c = 0; c < 8; ++c) {
      const int jb = w * 256 + c * 32 + klane * 8;
      f32x4 w0 = *(const f32x4*)(wr + jb),     m0 = *(const f32x4*)(mr + jb);
      f32x4 w1 = *(const f32x4*)(wr + jb + 4), m1 = *(const f32x4*)(mr + jb + 4);
      float wf[8] = { w0.x*m0.x, w0.y*m0.y, w0.z*m0.z, w0.w*m0.w,
                      w1.x*m1.x, w1.y*m1.y, w1.z*m1.z, w1.w*m1.w };
      #pragma unroll
      for (int i = 0; i < 8; ++i) {
        unsigned int uh = __float_as_uint(wf[i]) & 0xffff0000u;
        float fl = wf[i] - __uint_as_float(uh);
        ahi[c][i] = (short)(uh >> 16);
        alo[c][i] = (short)(__float_as_uint(fl) >> 16);
      }
    }
  }

  // ---- per-lane persistent state ----
  const int sidx = bo * H + row;
  float h  = h0[sidx], rr_ = r0[sidx], u = u0[sidx];
  float p  = prel[row], psyn = 1.0f / p;
  float wih = Wih[row], oih = offih[row];
  float wz = Whz[(row >> 7) * H + row] * Whzm[(row >> 7) * H + row];
  float ht = 1.0f / (1.0f + __expf(-8.0f * (h - 0.5f)));

  const float INV_TAU = 1.0f / 0.01f, INV_TD = 1.0f / 0.2f, INV_TF = 1.0f / 1.5f;
  // publish addr: 8-lane contiguous runs -> 4 lines/wave
  const int sidx3 = ((row >> 3) << 7) + (bo << 3) + (row & 7);  // [j>>3][b][j&7]

#define WAITV(n) { asm volatile("s_waitcnt vmcnt(" #n ")" ::: "memory"); \
                   __builtin_amdgcn_sched_barrier(0); }

  // ---- publish s_0 (tagged, fire-and-forget) ----
  {
    unsigned int pk = (pack_split(ht * rr_ * u * psyn) & ~1u) | TAG(0);
    unsigned int* ap = sbuf + sidx3;
    asm volatile("global_store_dword %0, %1, off sc0 sc1" :: "v"(ap), "v"(pk) : "memory");
  }

  float* ph = dout + H_OFF + (size_t)bo * (SEQ * H) + row;
  float* pr = dout + R_OFF + (size_t)bo * (SEQ * H) + row;
  float* pu = dout + U_OFF + (size_t)bo * (SEQ * H) + row;
  float* pz = zpart + (size_t)g * BATCH + (w << 2) + (lane >> 4);  // writer: (lane&15)==0
  const float* ip = Irep + bo;
  float Itc = ip[0];

// chunk c covers k = c*32 + klane*8 + [0,8)
#define ISSUE_CHUNK(c) { \
    const unsigned int* ap = sb + ((w * 32 + (c) * 4 + klane) * 128 + arow * 8); \
    asm volatile("global_load_dwordx4 %0, %1, off sc0 sc1" : "=v"(ld[2*(c)])   : "v"(ap)     : "memory"); \
    asm volatile("global_load_dwordx4 %0, %1, off sc0 sc1" : "=v"(ld[2*(c)+1]) : "v"(ap + 4) : "memory"); }

#define VCHK(c, okv) { u32x4 v0 = ld[2*(c)], v1 = ld[2*(c)+1]; \
    unsigned int bad = (v0.x ^ tg) | (v0.y ^ tg) | (v0.z ^ tg) | (v0.w ^ tg) \
                     | (v1.x ^ tg) | (v1.y ^ tg) | (v1.z ^ tg) | (v1.w ^ tg); \
    okv = __all((int)((bad & 1u) == 0)); }

// 3-term split product: hi*hi + hi*lo + lo*hi (lo*lo ~ 2^-16 relative, dropped)
#define DO_CHUNK(c) { \
    u32x4 q0 = ld[2*(c)], q1 = ld[2*(c)+1]; \
    s16x8 bh, bl; \
    bh[0]=(short)(q0.x>>16); bl[0]=(short)q0.x; \
    bh[1]=(short)(q0.y>>16); bl[1]=(short)q0.y; \
    bh[2]=(short)(q0.z>>16); bl[2]=(short)q0.z; \
    bh[3]=(short)(q0.w>>16); bl[3]=(short)q0.w; \
    bh[4]=(short)(q1.x>>16); bl[4]=(short)q1.x; \
    bh[5]=(short)(q1.y>>16); bl[5]=(short)q1.y; \
    bh[6]=(short)(q1.z>>16); bl[6]=(short)q1.z; \
    bh[7]=(short)(q1.w>>16); bl[7]=(short)q1.w; \
    acc = __builtin_amdgcn_mfma_f32_16x16x32_bf16(ahi[c], bh, acc, 0, 0, 0); \
    acc = __builtin_amdgcn_mfma_f32_16x16x32_bf16(ahi[c], bl, acc, 0, 0, 0); \
    acc = __builtin_amdgcn_mfma_f32_16x16x32_bf16(alo[c], bh, acc, 0, 0, 0); }

#define FIRST_PASS(c, n) { WAITV(n); int ok; VCHK(c, ok); \
    if (ok) { DO_CHUNK(c); done |= (1 << (c)); } }

  for (int t = 0; t < SEQ; ++t) {
    const unsigned int tg = TAG(t);
    const unsigned int* sb = sbuf + (t & 1) * (BATCH * H);

    // ---- adaptive ack (own publish retired; 5 newer tail ops may remain)
    //      + fixed margin for peer-publish spread (retry costs ~900cyc,
    //      margin costs 256 — R12 measured ~1.7:1 conversion) ----
    WAITV(5);
    asm volatile("s_sleep 4" :::);

    // ---- speculative slice load; per-chunk verify -> MFMA; retry stale chunks ----
    u32x4 ld[16];
    f32x4 acc = {0.f, 0.f, 0.f, 0.f};
    int done = 0;

    ISSUE_CHUNK(0) ISSUE_CHUNK(1) ISSUE_CHUNK(2) ISSUE_CHUNK(3)
    ISSUE_CHUNK(4) ISSUE_CHUNK(5) ISSUE_CHUNK(6) ISSUE_CHUNK(7)

    // ---- hide rec-independent state math under the load latency ----
    float rn  = rr_ + ((1.0f - rr_) * INV_TD - 50.0f * u * rr_ * ht) * 0.001f;
    float un  = u + ((p - u) * INV_TF + 50.0f * p * (1.0f - u) * ht) * 0.001f;
    float spre = rn * un * psyn;           // s_{t+1} = htn * spre
    float ext  = Itc * wih + oih;

    FIRST_PASS(0,14) FIRST_PASS(1,12) FIRST_PASS(2,10) FIRST_PASS(3,8)
    FIRST_PASS(4,6)  FIRST_PASS(5,4)  FIRST_PASS(6,2)  FIRST_PASS(7,0)

    {
      int guard = 0;
      while (done != 0xff && ++guard < (1 << 13)) {
        #pragma unroll
        for (int c = 0; c < 8; ++c)
          if (!(done & (1 << c))) ISSUE_CHUNK(c);
        WAITV(0);
        #pragma unroll
        for (int c = 0; c < 8; ++c)
          if (!(done & (1 << c))) {
            int ok; VCHK(c, ok);
            if (ok) { DO_CHUNK(c); done |= (1 << c); }
          }
      }
    }

    // ---- cross-wave K reduce (C: row=klane*4+i, col=arow) ----
    const int pbuf = t & 1;
    redC[pbuf][w][klane * 4 + 0][arow] = acc.x;
    redC[pbuf][w][klane * 4 + 1][arow] = acc.y;
    redC[pbuf][w][klane * 4 + 2][arow] = acc.z;
    redC[pbuf][w][klane * 4 + 3][arow] = acc.w;
    __syncthreads();
    float rec = redC[pbuf][0][ro][bo] + redC[pbuf][1][ro][bo]
              + redC[pbuf][2][ro][bo] + redC[pbuf][3][ro][bo];

    // ---- short rec-dependent tail ----
    float hn  = h + ((-h + rec + ext) * INV_TAU) * 0.001f;
    float htn = 1.0f / (1.0f + __expf(-8.0f * (hn - 0.5f)));

    // ---- publish s_{t+1}: tagged single store (coalesced runs), no ack ----
    {
      unsigned int pk = (pack_split(htn * spre) & ~1u) | TAG(t + 1);
      unsigned int* ap = sbuf + ((t + 1) & 1) * (BATCH * H) + sidx3;
      asm volatile("global_store_dword %0, %1, off sc0 sc1" :: "v"(ap), "v"(pk) : "memory");
    }

    // ---- outputs (off critical path; not waited by next head WAITV(5)) ----
    ph[(size_t)t * H] = hn; pr[(size_t)t * H] = rn; pu[(size_t)t * H] = un;
    float zl = htn * wz;
    zl += __shfl_xor(zl, 1); zl += __shfl_xor(zl, 2);
    zl += __shfl_xor(zl, 4); zl += __shfl_xor(zl, 8);   // sum over 16 rows (same bo)
    if ((lane & 15) == 0) pz[(size_t)t * (G * BATCH)] = zl;

    Itc = ip[(size_t)(t + 1) * BATCH];   // prefetch next I (pad covers t+1==SEQ)
    h = hn; ht = htn; rr_ = rn; u = un;
  }
#undef FIRST_PASS
#undef DO_CHUNK
#undef VCHK
#undef ISSUE_CHUNK
#undef WAITV
}

__global__ void zred_kernel(const float* __restrict__ zpart, const float* __restrict__ offhz,
                            float* __restrict__ zout) {
  int tid = blockIdx.x * blockDim.x + threadIdx.x;
  if (tid >= BATCH * SEQ * NOUT) return;
  int b = tid / (SEQ * NOUT);
  int rem = tid - b * (SEQ * NOUT);
  int t = rem >> 3, o = rem & 7;
  float acc = offhz[o];
  #pragma unroll
  for (int k = 0; k < G / NOUT; ++k)
    acc += zpart[((size_t)t * G + o * (G / NOUT) + k) * BATCH + b];
  zout[tid] = acc;
}

extern "C" void kernel_launch(void* const* d_in, const int* in_sizes, int n_in,
                              void* d_out, int out_size, void* d_ws, size_t ws_size,
                              hipStream_t stream) {
  const float* I     = (const float*)d_in[0];
  const float* h0    = (const float*)d_in[1];
  const float* r0    = (const float*)d_in[2];
  const float* u0    = (const float*)d_in[3];
  const float* Wih   = (const float*)d_in[4];
  const float* offih = (const float*)d_in[5];
  const float* Whh   = (const float*)d_in[6];
  const float* Whz   = (const float*)d_in[7];
  const float* offhz = (const float*)d_in[8];
  const float* prel  = (const float*)d_in[9];
  const float* Whhm  = (const float*)d_in[10];
  const float* Whzm  = (const float*)d_in[11];
  float* out = (float*)d_out;

  unsigned int* sbuf  = (unsigned int*)((char*)d_ws + SBUF_OFF);
  float* Irep  = (float*)((char*)d_ws + IREP_OFF);
  float* zpart = (float*)((char*)d_ws + ZPART_OFF);

  hipMemsetAsync(d_out, 0, (size_t)H_OFF * sizeof(float), stream);  // n_all == 0
  init_kernel<<<128, 256, 0, stream>>>(I, Irep, sbuf);
  rnn_persist<<<G, TPB, 0, stream>>>(h0, r0, u0, Wih, offih, Whh, Whz, prel, Whhm, Whzm,
                                     Irep, sbuf, zpart, out);
  zred_kernel<<<(BATCH * SEQ * NOUT + 255) / 256, 256, 0, stream>>>(zpart, offhz, out + Z_OFF);
}

// Round 17
// 3711.710 us; speedup vs baseline: 1.3375x; 1.0696x over previous
//
#include <hip/hip_runtime.h>
#include <cstdint>
#include <cstddef>

typedef float f32x4 __attribute__((ext_vector_type(4)));
typedef unsigned int u32x4 __attribute__((ext_vector_type(4)));
typedef short s16x8 __attribute__((ext_vector_type(8)));

#define H     1024
#define BATCH 16
#define SEQ   2000
#define NOUT  8
#define G     64       // persistent workgroups, 16 rows each
#define RPW   16
#define TPB   256

// d_out offsets (floats): n_all, h_all, r_all, u_all, z_all
#define H_OFF 32768000
#define R_OFF 65536000
#define U_OFF 98304000
#define Z_OFF 131072000

// ws layout (bytes)
#define SBUF_OFF  8192       // double-buffered packed s: 2*16384 u32
                             // layout [j>>3][(j>>2)&1][b][j&3] (instruction-contiguous)
#define IREP_OFF  139264     // I repacked [t][b] (+pad)
#define ZPART_OFF 267392     // zpart [t][g][b]

#define TAG(tau) ((unsigned int)(((tau) >> 1) & 1))

__global__ void init_kernel(const float* __restrict__ I, float* __restrict__ Irep,
                            unsigned int* __restrict__ sbuf) {
  int tid = blockIdx.x * blockDim.x + threadIdx.x;
  if (tid < SEQ * BATCH) {
    int t = tid >> 4, b = tid & 15;
    Irep[tid] = I[b * SEQ + t];            // I is [B, SEQ, 1]
  }
  if (tid < 2 * BATCH * H) {               // pre-tag both buffers stale (tag=1; s_0/s_1 expect 0)
    unsigned int* ap = sbuf + tid; unsigned int v = 1u;
    asm volatile("global_store_dword %0, %1, off sc0 sc1" :: "v"(ap), "v"(v) : "memory");
  }
}

// split f into truncated-bf16 hi + truncated-bf16 lo, packed (hi<<16)|lo
__device__ __forceinline__ unsigned int pack_split(float f) {
  unsigned int uh = __float_as_uint(f) & 0xffff0000u;
  float fl = f - __uint_as_float(uh);
  return uh | (__float_as_uint(fl) >> 16);
}

__global__ __launch_bounds__(TPB, 1) void rnn_persist(
    const float* __restrict__ h0, const float* __restrict__ r0, const float* __restrict__ u0,
    const float* __restrict__ Wih, const float* __restrict__ offih,
    const float* __restrict__ Whh, const float* __restrict__ Whz,
    const float* __restrict__ prel, const float* __restrict__ Whhm, const float* __restrict__ Whzm,
    const float* __restrict__ Irep, unsigned int* __restrict__ sbuf,
    float* __restrict__ zpart, float* __restrict__ dout)
{
  __shared__ float redC[2][4][16][17];   // [parity][wave][row][batch(+pad)]

  const int g = blockIdx.x, tid = threadIdx.x;
  const int lane = tid & 63, w = tid >> 6;
  const int arow  = lane & 15;           // MFMA A row / B col (batch)  [fragment role]
  const int klane = lane >> 4;           // 0..3: k-subgroup            [fragment role]
  const int ro = lane & 15;              // owned row within WG
  const int bo = (w << 2) + (lane >> 4); // owned batch
  const int row = g * RPW + ro;

  // ---- one-time: masked W_hh -> split-bf16 fragments in VGPRs (64 regs) ----
  s16x8 ahi[8], alo[8];
  {
    const float* wr = Whh  + (size_t)(g * RPW + arow) * H;
    const float* mr = Whhm + (size_t)(g * RPW + arow) * H;
    #pragma unroll
    for (int c = 0; c < 8; ++c) {
      const int jb = w * 256 + c * 32 + klane * 8;
      f32x4 w0 = *(const f32x4*)(wr + jb),     m0 = *(const f32x4*)(mr + jb);
      f32x4 w1 = *(const f32x4*)(wr + jb + 4), m1 = *(const f32x4*)(mr + jb + 4);
      float wf[8] = { w0.x*m0.x, w0.y*m0.y, w0.z*m0.z, w0.w*m0.w,
                      w1.x*m1.x, w1.y*m1.y, w1.z*m1.z, w1.w*m1.w };
      #pragma unroll
      for (int i = 0; i < 8; ++i) {
        unsigned int uh = __float_as_uint(wf[i]) & 0xffff0000u;
        float fl = wf[i] - __uint_as_float(uh);
        ahi[c][i] = (short)(uh >> 16);
        alo[c][i] = (short)(__float_as_uint(fl) >> 16);
      }
    }
  }

  // ---- per-lane persistent state ----
  const int sidx = bo * H + row;
  float h  = h0[sidx], rr_ = r0[sidx], u = u0[sidx];
  float p  = prel[row], psyn = 1.0f / p;
  float wih = Wih[row], oih = offih[row];
  float wz = Whz[(row >> 7) * H + row] * Whzm[(row >> 7) * H + row];
  float ht = 1.0f / (1.0f + __expf(-8.0f * (h - 0.5f)));

  const float INV_TAU = 1.0f / 0.01f, INV_TD = 1.0f / 0.2f, INV_TF = 1.0f / 1.5f;
  // publish index in [j>>3][(j>>2)&1][b][j&3] layout
  const int sidx3 = ((row >> 3) << 7) + (((row >> 2) & 1) << 6) + (bo << 2) + (row & 3);

#define WAITV(n) { asm volatile("s_waitcnt vmcnt(" #n ")" ::: "memory"); \
                   __builtin_amdgcn_sched_barrier(0); }

  // ---- publish s_0 (tagged, fire-and-forget) ----
  {
    unsigned int pk = (pack_split(ht * rr_ * u * psyn) & ~1u) | TAG(0);
    unsigned int* ap = sbuf + sidx3;
    asm volatile("global_store_dword %0, %1, off sc0 sc1" :: "v"(ap), "v"(pk) : "memory");
  }

  float* ph = dout + H_OFF + (size_t)bo * (SEQ * H) + row;
  float* pr = dout + R_OFF + (size_t)bo * (SEQ * H) + row;
  float* pu = dout + U_OFF + (size_t)bo * (SEQ * H) + row;
  float* pz = zpart + (size_t)g * BATCH + (w << 2) + (lane >> 4);  // writer: (lane&15)==0
  const float* ip = Irep + bo;
  float Itc = ip[0];

// chunk c covers k = c*32 + klane*8 + [0,8)
// instruction q in {0,1}: 16 lanes x 16B CONTIGUOUS (fully-used lines; the two
// instructions touch disjoint lines -> 2x fewer MALL line-transactions)
#define ISSUE_CHUNK(c) { \
    const unsigned int* ap = sb + (((w * 32 + (c) * 4 + klane) << 7) + (arow << 2)); \
    asm volatile("global_load_dwordx4 %0, %1, off sc0 sc1" : "=v"(ld[2*(c)])   : "v"(ap)      : "memory"); \
    asm volatile("global_load_dwordx4 %0, %1, off sc0 sc1" : "=v"(ld[2*(c)+1]) : "v"(ap + 64) : "memory"); }

#define VCHK(c, okv) { u32x4 v0 = ld[2*(c)], v1 = ld[2*(c)+1]; \
    unsigned int bad = (v0.x ^ tg) | (v0.y ^ tg) | (v0.z ^ tg) | (v0.w ^ tg) \
                     | (v1.x ^ tg) | (v1.y ^ tg) | (v1.z ^ tg) | (v1.w ^ tg); \
    okv = __all((int)((bad & 1u) == 0)); }

// 3-term split product: hi*hi + hi*lo + lo*hi (lo*lo ~ 2^-16 relative, dropped)
// ld[2c] = k-offsets 0..3 (q=0), ld[2c+1] = k-offsets 4..7 (q=1) — same as before
#define DO_CHUNK(c) { \
    u32x4 q0 = ld[2*(c)], q1 = ld[2*(c)+1]; \
    s16x8 bh, bl; \
    bh[0]=(short)(q0.x>>16); bl[0]=(short)q0.x; \
    bh[1]=(short)(q0.y>>16); bl[1]=(short)q0.y; \
    bh[2]=(short)(q0.z>>16); bl[2]=(short)q0.z; \
    bh[3]=(short)(q0.w>>16); bl[3]=(short)q0.w; \
    bh[4]=(short)(q1.x>>16); bl[4]=(short)q1.x; \
    bh[5]=(short)(q1.y>>16); bl[5]=(short)q1.y; \
    bh[6]=(short)(q1.z>>16); bl[6]=(short)q1.z; \
    bh[7]=(short)(q1.w>>16); bl[7]=(short)q1.w; \
    acc = __builtin_amdgcn_mfma_f32_16x16x32_bf16(ahi[c], bh, acc, 0, 0, 0); \
    acc = __builtin_amdgcn_mfma_f32_16x16x32_bf16(ahi[c], bl, acc, 0, 0, 0); \
    acc = __builtin_amdgcn_mfma_f32_16x16x32_bf16(alo[c], bh, acc, 0, 0, 0); }

#define FIRST_PASS(c, n) { WAITV(n); int ok; VCHK(c, ok); \
    if (ok) { DO_CHUNK(c); done |= (1 << (c)); } }

  for (int t = 0; t < SEQ; ++t) {
    const unsigned int tg = TAG(t);
    const unsigned int* sb = sbuf + (t & 1) * (BATCH * H);

    // adaptive ack (own publish retired; 5 newer tail ops may remain) + margin
    WAITV(5);
    asm volatile("s_sleep 4" :::);

    u32x4 ld[16];
    f32x4 acc = {0.f, 0.f, 0.f, 0.f};
    int done = 0;

    ISSUE_CHUNK(0) ISSUE_CHUNK(1) ISSUE_CHUNK(2) ISSUE_CHUNK(3)
    ISSUE_CHUNK(4) ISSUE_CHUNK(5) ISSUE_CHUNK(6) ISSUE_CHUNK(7)

    // hide rec-independent state math under the load latency
    float rn  = rr_ + ((1.0f - rr_) * INV_TD - 50.0f * u * rr_ * ht) * 0.001f;
    float un  = u + ((p - u) * INV_TF + 50.0f * p * (1.0f - u) * ht) * 0.001f;
    float spre = rn * un * psyn;           // s_{t+1} = htn * spre
    float ext  = Itc * wih + oih;

    FIRST_PASS(0,14) FIRST_PASS(1,12) FIRST_PASS(2,10) FIRST_PASS(3,8)
    FIRST_PASS(4,6)  FIRST_PASS(5,4)  FIRST_PASS(6,2)  FIRST_PASS(7,0)

    {
      int guard = 0;
      while (done != 0xff && ++guard < (1 << 13)) {
        #pragma unroll
        for (int c = 0; c < 8; ++c)
          if (!(done & (1 << c))) ISSUE_CHUNK(c);
        WAITV(0);
        #pragma unroll
        for (int c = 0; c < 8; ++c)
          if (!(done & (1 << c))) {
            int ok; VCHK(c, ok);
            if (ok) { DO_CHUNK(c); done |= (1 << c); }
          }
      }
    }

    // ---- cross-wave K reduce (C: row=klane*4+i, col=arow) ----
    const int pbuf = t & 1;
    redC[pbuf][w][klane * 4 + 0][arow] = acc.x;
    redC[pbuf][w][klane * 4 + 1][arow] = acc.y;
    redC[pbuf][w][klane * 4 + 2][arow] = acc.z;
    redC[pbuf][w][klane * 4 + 3][arow] = acc.w;
    __syncthreads();
    float rec = redC[pbuf][0][ro][bo] + redC[pbuf][1][ro][bo]
              + redC[pbuf][2][ro][bo] + redC[pbuf][3][ro][bo];

    // ---- short rec-dependent tail ----
    float hn  = h + ((-h + rec + ext) * INV_TAU) * 0.001f;
    float htn = 1.0f / (1.0f + __expf(-8.0f * (hn - 0.5f)));

    // ---- publish s_{t+1}: tagged single store, no ack, no flags ----
    {
      unsigned int pk = (pack_split(htn * spre) & ~1u) | TAG(t + 1);
      unsigned int* ap = sbuf + ((t + 1) & 1) * (BATCH * H) + sidx3;
      asm volatile("global_store_dword %0, %1, off sc0 sc1" :: "v"(ap), "v"(pk) : "memory");
    }

    // ---- outputs (off critical path; not waited by next head WAITV(5)) ----
    ph[(size_t)t * H] = hn; pr[(size_t)t * H] = rn; pu[(size_t)t * H] = un;
    float zl = htn * wz;
    zl += __shfl_xor(zl, 1); zl += __shfl_xor(zl, 2);
    zl += __shfl_xor(zl, 4); zl += __shfl_xor(zl, 8);   // sum over 16 rows (same bo)
    if ((lane & 15) == 0) pz[(size_t)t * (G * BATCH)] = zl;

    Itc = ip[(size_t)(t + 1) * BATCH];   // prefetch next I (pad covers t+1==SEQ)
    h = hn; ht = htn; rr_ = rn; u = un;
  }
#undef FIRST_PASS
#undef DO_CHUNK
#undef VCHK
#undef ISSUE_CHUNK
#undef WAITV
}

__global__ void zred_kernel(const float* __restrict__ zpart, const float* __restrict__ offhz,
                            float* __restrict__ zout) {
  int tid = blockIdx.x * blockDim.x + threadIdx.x;
  if (tid >= BATCH * SEQ * NOUT) return;
  int b = tid / (SEQ * NOUT);
  int rem = tid - b * (SEQ * NOUT);
  int t = rem >> 3, o = rem & 7;
  float acc = offhz[o];
  #pragma unroll
  for (int k = 0; k < G / NOUT; ++k)
    acc += zpart[((size_t)t * G + o * (G / NOUT) + k) * BATCH + b];
  zout[tid] = acc;
}

extern "C" void kernel_launch(void* const* d_in, const int* in_sizes, int n_in,
                              void* d_out, int out_size, void* d_ws, size_t ws_size,
                              hipStream_t stream) {
  const float* I     = (const float*)d_in[0];
  const float* h0    = (const float*)d_in[1];
  const float* r0    = (const float*)d_in[2];
  const float* u0    = (const float*)d_in[3];
  const float* Wih   = (const float*)d_in[4];
  const float* offih = (const float*)d_in[5];
  const float* Whh   = (const float*)d_in[6];
  const float* Whz   = (const float*)d_in[7];
  const float* offhz = (const float*)d_in[8];
  const float* prel  = (const float*)d_in[9];
  const float* Whhm  = (const float*)d_in[10];
  const float* Whzm  = (const float*)d_in[11];
  float* out = (float*)d_out;

  unsigned int* sbuf  = (unsigned int*)((char*)d_ws + SBUF_OFF);
  float* Irep  = (float*)((char*)d_ws + IREP_OFF);
  float* zpart = (float*)((char*)d_ws + ZPART_OFF);

  hipMemsetAsync(d_out, 0, (size_t)H_OFF * sizeof(float), stream);  // n_all == 0
  init_kernel<<<128, 256, 0, stream>>>(I, Irep, sbuf);
  rnn_persist<<<G, TPB, 0, stream>>>(h0, r0, u0, Wih, offih, Whh, Whz, prel, Whhm, Whzm,
                                     Irep, sbuf, zpart, out);
  zred_kernel<<<(BATCH * SEQ * NOUT + 255) / 256, 256, 0, stream>>>(zpart, offhz, out + Z_OFF);
}